// Round 8
// baseline (666.915 us; speedup 1.0000x reference)
//
#include <hip/hip_runtime.h>

#define NN     2048
#define DIM    512
#define QKS    1024
#define NH     8
#define HD     64
#define NE     32768
#define EPAD   32832
#define CH2    8
#define LOG2E  1.4426950408889634f

typedef __attribute__((ext_vector_type(8))) short bf16x8;
typedef __attribute__((ext_vector_type(4))) float f32x4;
typedef __attribute__((ext_vector_type(4))) unsigned int u32x4;

#define MFMA(a,b,c) __builtin_amdgcn_mfma_f32_16x16x32_bf16((a),(b),(c),0,0,0)

__device__ __forceinline__ float bf2f(unsigned int u16){
  union { unsigned int i; float f; } v; v.i = u16 << 16; return v.f;
}
__device__ __forceinline__ unsigned short f2bf(float f){
  union { float ff; unsigned int i; } v; v.ff = f;
  return (unsigned short)((v.i + 0x7fffu + ((v.i >> 16) & 1u)) >> 16);
}
__device__ __forceinline__ void acc8(float* b, u32x4 v){
  b[0] += bf2f(v[0] & 0xffffu); b[1] += bf2f(v[0] >> 16);
  b[2] += bf2f(v[1] & 0xffffu); b[3] += bf2f(v[1] >> 16);
  b[4] += bf2f(v[2] & 0xffffu); b[5] += bf2f(v[2] >> 16);
  b[6] += bf2f(v[3] & 0xffffu); b[7] += bf2f(v[3] >> 16);
}
__device__ __forceinline__ bf16x8 pack8(float4 x0, float4 x1){
  bf16x8 v;
  v[0]=(short)f2bf(x0.x); v[1]=(short)f2bf(x0.y); v[2]=(short)f2bf(x0.z); v[3]=(short)f2bf(x0.w);
  v[4]=(short)f2bf(x1.x); v[5]=(short)f2bf(x1.y); v[6]=(short)f2bf(x1.z); v[7]=(short)f2bf(x1.w);
  return v;
}

// ================= prep_k: [0,512) X fp32->bf16 | [512,1536) weight transposes =================
__global__ __launch_bounds__(256) void prep_k(
    const float* __restrict__ X,
    const float* __restrict__ WQ, const float* __restrict__ WK,
    const float* __restrict__ WV, const float* __restrict__ WO,
    unsigned short* __restrict__ Xb, unsigned short* __restrict__ Wt)
{
  __shared__ unsigned short tile[32][33];
  int idx = blockIdx.x, tid = threadIdx.x;
  if (idx < 512){
    long off = (long)idx*256 + tid;          // 8-elem group
    const float* p = X + off*8;
    float4 x0 = *(const float4*)p, x1 = *(const float4*)(p+4);
    bf16x8 v = pack8(x0, x1);
    *(bf16x8*)(Xb + off*8) = v;
    return;
  }
  int b = idx - 512;
  int z = b >> 8, t = b & 255;
  const float* src = z==0 ? WQ : z==1 ? WK : z==2 ? WV : WO;
  unsigned short* dst = Wt + (size_t)z*DIM*DIM;
  int bx = (t & 15)*32, by = (t >> 4)*32;
  int tx = tid & 31, ty = tid >> 5;
  #pragma unroll
  for (int i=0;i<32;i+=8) tile[ty+i][tx] = f2bf(src[(size_t)(by+ty+i)*DIM + bx+tx]);
  __syncthreads();
  #pragma unroll
  for (int i=0;i<32;i+=8) dst[(size_t)(bx+ty+i)*DIM + by+tx] = tile[tx][ty+i];
}

// ================= t2f_k: T2L[l][e][h] = ef[e]·ew[l*8+h], direct from fp32 =================
// grid 129 x 256; wave covers 64 e-rows; e >= NE and lh >= 40 are zero (covers sentinel e=NE).
__global__ __launch_bounds__(256) void t2f_k(
    const float* __restrict__ ef, const float* __restrict__ ew,
    unsigned short* __restrict__ T2L)
{
  int lane = threadIdx.x & 63, w = threadIdx.x >> 6;
  int quad = lane >> 4, low = lane & 15;
  int m0 = blockIdx.x*256 + w*64;
  f32x4 acc[4][3];
  #pragma unroll
  for (int im=0;im<4;im++)
    #pragma unroll
    for (int t=0;t<3;t++) acc[im][t] = (f32x4){0.f,0.f,0.f,0.f};
  #pragma unroll
  for (int k0=0;k0<64;k0+=32){
    bf16x8 a[4], b[3];
    #pragma unroll
    for (int im=0;im<4;im++){
      int e = m0 + im*16 + low;
      bf16x8 v = (bf16x8){0,0,0,0,0,0,0,0};
      if (e < NE){
        const float* p = ef + (size_t)e*64 + k0 + quad*8;
        v = pack8(*(const float4*)p, *(const float4*)(p+4));
      }
      a[im] = v;
    }
    #pragma unroll
    for (int t=0;t<3;t++){
      int lh = 16*t + low;
      bf16x8 v = (bf16x8){0,0,0,0,0,0,0,0};
      if (lh < 40){
        const float* p = ew + (size_t)lh*64 + k0 + quad*8;
        v = pack8(*(const float4*)p, *(const float4*)(p+4));
      }
      b[t] = v;
    }
    #pragma unroll
    for (int im=0;im<4;im++)
      #pragma unroll
      for (int t=0;t<3;t++) acc[im][t] = MFMA(a[im], b[t], acc[im][t]);
  }
  #pragma unroll
  for (int im=0;im<4;im++){
    #pragma unroll
    for (int t=0;t<3;t++){
      #pragma unroll
      for (int r=0;r<4;r++){
        int row = m0 + im*16 + quad*4 + r;
        int col = 16*t + low;
        if (row < EPAD && col < 40)
          T2L[((size_t)(col>>3)*EPAD + row)*8 + (col&7)] = f2bf(acc[im][t][r]);
      }
    }
  }
}

// ============ gemm: C[M][N] = A1[M][K]·A2[N][K]^T + bias; wave tile 64x64 ============
// 8 loads per 16 MFMA (2.5x fewer loads/MFMA than 16x64 wave tile).
__global__ __launch_bounds__(256) void gemm_bt(
    const unsigned short* __restrict__ A1, const unsigned short* __restrict__ A2,
    const float* __restrict__ biasA, const float* __restrict__ biasB,
    unsigned short* __restrict__ C, float* __restrict__ Cf,
    int N, int K, int bias_row)
{
  int lane = threadIdx.x & 63, w = threadIdx.x >> 6;
  int quad = lane >> 4, low = lane & 15;
  int m0 = blockIdx.y*256 + w*64;
  int n0 = blockIdx.x*64;
  f32x4 acc[4][4];
  #pragma unroll
  for (int im=0;im<4;im++)
    #pragma unroll
    for (int t=0;t<4;t++) acc[im][t] = (f32x4){0.f,0.f,0.f,0.f};
  for (int k0=0; k0<K; k0+=32){
    bf16x8 a[4], b[4];
    #pragma unroll
    for (int im=0;im<4;im++)
      a[im] = *(const bf16x8*)(A1 + (size_t)(m0+im*16+low)*K + k0 + quad*8);
    #pragma unroll
    for (int t=0;t<4;t++)
      b[t] = *(const bf16x8*)(A2 + (size_t)(n0+16*t+low)*K + k0 + quad*8);
    #pragma unroll
    for (int im=0;im<4;im++)
      #pragma unroll
      for (int t=0;t<4;t++) acc[im][t] = MFMA(a[im], b[t], acc[im][t]);
  }
  #pragma unroll
  for (int im=0;im<4;im++){
    #pragma unroll
    for (int t=0;t<4;t++){
      #pragma unroll
      for (int r=0;r<4;r++){
        int row = m0 + im*16 + quad*4 + r;
        int col = n0 + 16*t + low;
        float v = acc[im][t][r];
        if (biasA){
          int bi = bias_row ? row : col;
          v += (bi < 512) ? biasA[bi] : biasB[bi-512];
        }
        if (Cf) Cf[(size_t)row*N + col] = v;
        else    C [(size_t)row*N + col] = f2bf(v);
      }
    }
  }
}

// ===== bias_k: 2 pixels/thread, 10 nontemporal gathers in flight before any use =====
__global__ __launch_bounds__(256) void bias_k(
    const float* __restrict__ spb, const int* __restrict__ dist,
    const int* __restrict__ sp, const int* __restrict__ maskp,
    const unsigned short* __restrict__ T2L, unsigned short* __restrict__ biasBuf)
{
  int p0 = blockIdx.x*512 + threadIdx.x;   // grid = NN*NN/512
  int p1 = p0 + 256;
  const int* s0 = sp + (size_t)p0*5;
  const int* s1 = sp + (size_t)p1*5;
  int e[10];
  #pragma unroll
  for (int l=0;l<5;l++){ e[l] = s0[l]; e[5+l] = s1[l]; }
  #pragma unroll
  for (int l=0;l<10;l++) if ((unsigned)e[l] > (unsigned)NE) e[l] = NE;
  u32x4 t[10];
  #pragma unroll
  for (int l=0;l<5;l++){
    t[l]   = __builtin_nontemporal_load((const u32x4*)(T2L + ((size_t)l*EPAD + e[l])*8));
    t[5+l] = __builtin_nontemporal_load((const u32x4*)(T2L + ((size_t)l*EPAD + e[5+l])*8));
  }
  int d0 = dist[p0], d1 = dist[p1];
  int m0 = maskp[p0], m1 = maskp[p1];
  d0 = d0 < 0 ? 0 : (d0 > 5 ? 5 : d0);
  d1 = d1 < 0 ? 0 : (d1 > 5 ? 5 : d1);
  float b0[8], b1[8];
  #pragma unroll
  for (int x=0;x<8;x++){ b0[x] = spb[d0*8 + x]; b1[x] = spb[d1*8 + x]; }
  #pragma unroll
  for (int l=0;l<5;l++){ acc8(b0, t[l]); acc8(b1, t[5+l]); }
  unsigned short o0[8], o1[8];
  #pragma unroll
  for (int x=0;x<8;x++){
    o0[x] = f2bf(m0 ? -1e30f : b0[x]);
    o1[x] = f2bf(m1 ? -1e30f : b1[x]);
  }
  *(uint4*)(biasBuf + (size_t)p0*8) = *(const uint4*)o0;
  *(uint4*)(biasBuf + (size_t)p1*8) = *(const uint4*)o1;
}

// ================= attn2: streams precomputed bias; bf16 score/P LDS =================
// grid (128, CH2); block 512 = 8 waves, wave h = head h; chunk = 256 m = 4 tiles.
// Softmax is over HEADS per (q,m) pair (reference: softmax axis=-1 on (n,m,h)).
__global__ __launch_bounds__(512) void attn2_k(
    const unsigned short* __restrict__ Qb, const unsigned short* __restrict__ Kb,
    const unsigned short* __restrict__ Vt, const unsigned short* __restrict__ biasBuf,
    unsigned short* __restrict__ partO)
{
  __shared__ __attribute__((aligned(16))) unsigned short sldb[NH][16][72];  // 18.4 KB, row=144B
  int tid = threadIdx.x;
  int lane = tid & 63, h = tid >> 6;
  int quad = lane >> 4, low = lane & 15;
  int q0 = blockIdx.x * 16;
  int chunk = blockIdx.y;

  bf16x8 aq[2];
  #pragma unroll
  for (int s=0;s<2;s++)
    aq[s] = *(const bf16x8*)(Qb + (size_t)(q0+low)*QKS + h*HD + s*32 + quad*8);

  f32x4 accO[4];
  #pragma unroll
  for (int t=0;t<4;t++) accO[t] = (f32x4){0.f,0.f,0.f,0.f};

  uint4 bpf[2];
  #pragma unroll
  for (int it=0; it<2; ++it){
    int p = tid + it*512; int qq = p >> 6, mm = p & 63;
    bpf[it] = *(const uint4*)(biasBuf + ((size_t)(q0+qq)*NN + chunk*256 + mm)*8);
  }

  for (int jt=0; jt<4; ++jt){
    int m0 = chunk*256 + jt*64;
    __syncthreads();   // WAR: previous phase-D readers done

    // ---- phase B (wave h): S = Q K^T * 0.125 -> bf16 LDS ----
    f32x4 S[4];
    #pragma unroll
    for (int t=0;t<4;t++) S[t] = (f32x4){0.f,0.f,0.f,0.f};
    #pragma unroll
    for (int s=0;s<2;s++){
      #pragma unroll
      for (int t=0;t<4;t++){
        bf16x8 bk = *(const bf16x8*)(Kb + (size_t)(m0+16*t+low)*QKS + h*HD + s*32 + quad*8);
        S[t] = MFMA(aq[s], bk, S[t]);
      }
    }
    #pragma unroll
    for (int t=0;t<4;t++){
      #pragma unroll
      for (int r=0;r<4;r++)
        sldb[h][quad*4+r][low+16*t] = f2bf(S[t][r]*0.125f);
    }
    __syncthreads();

    // ---- phase C (coop): + bias, softmax over 8 heads per pair, P -> bf16 LDS ----
    #pragma unroll
    for (int it=0; it<2; ++it){
      int p = tid + it*512;
      int qq = p >> 6, mm = p & 63;
      uint4 bv = bpf[it];
      if (jt < 3)
        bpf[it] = *(const uint4*)(biasBuf + ((size_t)(q0+qq)*NN + m0 + 64 + mm)*8);
      float s0[8];
      s0[0] = bf2f(sldb[0][qq][mm]) + bf2f(bv.x & 0xffffu);
      s0[1] = bf2f(sldb[1][qq][mm]) + bf2f(bv.x >> 16);
      s0[2] = bf2f(sldb[2][qq][mm]) + bf2f(bv.y & 0xffffu);
      s0[3] = bf2f(sldb[3][qq][mm]) + bf2f(bv.y >> 16);
      s0[4] = bf2f(sldb[4][qq][mm]) + bf2f(bv.z & 0xffffu);
      s0[5] = bf2f(sldb[5][qq][mm]) + bf2f(bv.z >> 16);
      s0[6] = bf2f(sldb[6][qq][mm]) + bf2f(bv.w & 0xffffu);
      s0[7] = bf2f(sldb[7][qq][mm]) + bf2f(bv.w >> 16);
      float mx = s0[0];
      #pragma unroll
      for (int x=1;x<8;x++) mx = fmaxf(mx, s0[x]);
      float sum = 0.f;
      #pragma unroll
      for (int x=0;x<8;x++){ s0[x] = exp2f((s0[x]-mx)*LOG2E); sum += s0[x]; }
      float inv = (mx < -1e29f) ? 0.f : 1.f/sum;
      #pragma unroll
      for (int x=0;x<8;x++) sldb[x][qq][mm] = f2bf(s0[x]*inv);
    }
    __syncthreads();

    // ---- phase D (wave h): O += P V ; A-frags read directly as bf16x8 from LDS ----
    #pragma unroll
    for (int s=0;s<2;s++){
      bf16x8 ap = *(const bf16x8*)&sldb[h][low][s*32 + quad*8];
      #pragma unroll
      for (int t=0;t<4;t++){
        bf16x8 bv = *(const bf16x8*)(Vt + (size_t)(h*HD + 16*t + low)*NN + m0 + s*32 + quad*8);
        accO[t] = MFMA(ap, bv, accO[t]);
      }
    }
  }

  #pragma unroll
  for (int t=0;t<4;t++){
    #pragma unroll
    for (int r=0;r<4;r++){
      int q = quad*4 + r;
      partO[((size_t)chunk*NN + q0 + q)*DIM + h*HD + 16*t + low] = f2bf(accO[t][r]);
    }
  }
}

// ---------------- merge CH2 bf16 partials -> Obf ----------------
__global__ __launch_bounds__(512) void merge_k(const unsigned short* __restrict__ pb,
                                               unsigned short* __restrict__ Obf)
{
  size_t idx = (size_t)blockIdx.x*512 + threadIdx.x;
  float s = 0.f;
  #pragma unroll
  for (int c=0;c<CH2;c++) s += bf2f(pb[(size_t)c*NN*DIM + idx]);
  Obf[idx] = f2bf(s);
}

extern "C" void kernel_launch(void* const* d_in, const int* in_sizes, int n_in,
                              void* d_out, int out_size, void* d_ws, size_t ws_size,
                              hipStream_t stream)
{
  const float* X    = (const float*)d_in[0];
  const int*  dist  = (const int*)d_in[3];
  const int*  sp    = (const int*)d_in[4];
  const float* ef   = (const float*)d_in[5];
  const int*  maskp = (const int*)d_in[6];
  const float* WQ   = (const float*)d_in[7];
  const float* bQ   = (const float*)d_in[8];
  const float* WK   = (const float*)d_in[9];
  const float* bK   = (const float*)d_in[10];
  const float* WV   = (const float*)d_in[11];
  const float* bV   = (const float*)d_in[12];
  const float* WO   = (const float*)d_in[13];
  const float* bO   = (const float*)d_in[14];
  const float* spb  = (const float*)d_in[15];
  const float* ew   = (const float*)d_in[16];

  char* ws = (char*)d_ws;
  unsigned short* Wt      = (unsigned short*)(ws + 0);         // 4 x 512x512 bf16 (WQ^T,WK^T,WV^T,WO^T)
  unsigned short* Xb      = (unsigned short*)(ws + 2097152);   // 2048x512 bf16
  unsigned short* QKb     = (unsigned short*)(ws + 4194304);   // 2048x1024 bf16 (Q|K)
  unsigned short* Vtb     = (unsigned short*)(ws + 8388608);   // 512x2048 bf16 (V^T)
  unsigned short* T2L     = (unsigned short*)(ws + 10485760);  // 5 x EPAD x 8 bf16 (2.6 MB)
  unsigned short* Obf     = (unsigned short*)(ws + 13112320);  // 2048x512 bf16
  unsigned short* partO   = (unsigned short*)(ws + 15209472);  // CH2 x 2048x512 bf16 (16.8 MB)
  unsigned short* biasBuf = (unsigned short*)(ws + 31986688);  // NN x NN x 8 bf16 (67.1 MB); total 94.5 MB

  prep_k<<<dim3(1536), dim3(256), 0, stream>>>(X, WQ, WK, WV, WO, Xb, Wt);
  t2f_k<<<dim3(129), dim3(256), 0, stream>>>(ef, ew, T2L);
  // fused Q|K projection: C[2048][1024] = Xb · [WQ^T|WK^T]^T + [bQ|bK]
  gemm_bt<<<dim3(16,8), dim3(256), 0, stream>>>(Xb, Wt, bQ, bK, QKb, (float*)nullptr, QKS, DIM, 0);
  // V^T[512][2048] = WV^T · Xb^T + bV (row bias)
  gemm_bt<<<dim3(32,2), dim3(256), 0, stream>>>(Wt + 524288, Xb, bV, (const float*)nullptr, Vtb, (float*)nullptr, NN, DIM, 1);
  bias_k<<<dim3(8192), dim3(256), 0, stream>>>(spb, dist, sp, maskp, T2L, biasBuf);
  attn2_k<<<dim3(128,CH2), dim3(512), 0, stream>>>(QKb, QKb + 512, Vtb, biasBuf, partO);
  merge_k<<<dim3(2048), dim3(512), 0, stream>>>(partO, Obf);
  gemm_bt<<<dim3(8,8), dim3(256), 0, stream>>>(Obf, Wt + 786432, bO, bO, (unsigned short*)nullptr, (float*)d_out, DIM, DIM, 0);
}